// Round 2
// baseline (5881.199 us; speedup 1.0000x reference)
//
#include <hip/hip_runtime.h>
#include <hip/hip_bf16.h>
#include <math.h>

#define S_LEN 1024
#define B_SZ  2
#define D_DIM 1024
#define NHEAD 16
#define HDIM  64
#define EA_N  4
#define KA_K  2
#define EF_N  8
#define KF_K  2
#define FF_DIM 2048
#define NTOK  (S_LEN*B_SZ)
#define LN_EPS 1e-5f

// ---------------- LayerNorm + router logits (fused) ----------------
template<int E>
__global__ __launch_bounds__(256) void ln_gate_kernel(
    const float* __restrict__ x, const float* __restrict__ gamma,
    const float* __restrict__ beta, const float* __restrict__ Wg,
    float* __restrict__ h, float* __restrict__ logits)
{
    __shared__ float rA[4], rB[4], rG[4];
    __shared__ float stat[2];
    const int r = blockIdx.x;
    const int t = threadIdx.x;
    const int lane = t & 63, w = t >> 6;
    const size_t base = (size_t)r * D_DIM + t * 4;
    float4 xv = *(const float4*)(x + base);
    float s  = xv.x + xv.y + xv.z + xv.w;
    float sq = xv.x*xv.x + xv.y*xv.y + xv.z*xv.z + xv.w*xv.w;
    #pragma unroll
    for (int o = 32; o; o >>= 1) { s += __shfl_down(s, o); sq += __shfl_down(sq, o); }
    if (lane == 0) { rA[w] = s; rB[w] = sq; }
    __syncthreads();
    if (t == 0) {
        float ts = rA[0]+rA[1]+rA[2]+rA[3];
        float tq = rB[0]+rB[1]+rB[2]+rB[3];
        float mean = ts * (1.0f / D_DIM);
        float var  = tq * (1.0f / D_DIM) - mean * mean;
        stat[0] = mean;
        stat[1] = rsqrtf(var + LN_EPS);
    }
    __syncthreads();
    const float mean = stat[0], rstd = stat[1];
    float4 g4 = *(const float4*)(gamma + t*4);
    float4 b4 = *(const float4*)(beta  + t*4);
    float hv[4];
    hv[0] = (xv.x - mean) * rstd * g4.x + b4.x;
    hv[1] = (xv.y - mean) * rstd * g4.y + b4.y;
    hv[2] = (xv.z - mean) * rstd * g4.z + b4.z;
    hv[3] = (xv.w - mean) * rstd * g4.w + b4.w;
    *(float4*)(h + base) = make_float4(hv[0], hv[1], hv[2], hv[3]);
    #pragma unroll
    for (int e = 0; e < E; ++e) {
        float p = hv[0]*Wg[(t*4+0)*E+e] + hv[1]*Wg[(t*4+1)*E+e]
                + hv[2]*Wg[(t*4+2)*E+e] + hv[3]*Wg[(t*4+3)*E+e];
        #pragma unroll
        for (int o = 32; o; o >>= 1) p += __shfl_down(p, o);
        if (lane == 0) rG[w] = p;
        __syncthreads();
        if (t == 0) logits[(size_t)r*E + e] = rG[0]+rG[1]+rG[2]+rG[3];
        __syncthreads();
    }
}

// ---------------- softmax + top-k gates + aux accumulators ----------------
// acc layout: [importance E][load E][z_sum]
template<int E, int K>
__global__ __launch_bounds__(256) void gating_kernel(
    const float* __restrict__ logits, const unsigned char* __restrict__ halt,
    float* __restrict__ gates, float* __restrict__ acc)
{
    const int r = blockIdx.x * 256 + threadIdx.x;
    if (r >= NTOK) return;
    float l[E], p[E];
    float m = -1e30f;
    #pragma unroll
    for (int e = 0; e < E; ++e) { l[e] = logits[(size_t)r*E + e]; m = fmaxf(m, l[e]); }
    float sum = 0.f;
    #pragma unroll
    for (int e = 0; e < E; ++e) { p[e] = expf(l[e] - m); sum += p[e]; }
    const float inv = 1.0f / sum;
    #pragma unroll
    for (int e = 0; e < E; ++e) p[e] *= inv;     // probs
    unsigned used = 0u;
    float vsum = 0.f;
    int   idx[K]; float val[K];
    #pragma unroll
    for (int kk = 0; kk < K; ++kk) {
        float best = -1.f; int bi = 0;
        #pragma unroll
        for (int e = 0; e < E; ++e)
            if (!((used >> e) & 1u) && p[e] > best) { best = p[e]; bi = e; }
        idx[kk] = bi; val[kk] = best; used |= (1u << bi); vsum += best;
    }
    const float rn = 1.0f / (vsum + 1e-9f);
    const bool hlt = (halt[r] != 0);
    float g[E];
    #pragma unroll
    for (int e = 0; e < E; ++e) g[e] = 0.f;
    #pragma unroll
    for (int kk = 0; kk < K; ++kk) g[idx[kk]] = val[kk] * rn;
    #pragma unroll
    for (int e = 0; e < E; ++e) {
        float gg = hlt ? 0.f : g[e];
        gates[(size_t)r*E + e] = gg;
        atomicAdd(&acc[e], p[e]);                    // importance
        if (gg > 0.f) atomicAdd(&acc[E + e], 1.0f);  // load
    }
    const float lse = m + logf(sum);
    atomicAdd(&acc[2*E], lse * lse);
}

// ---------------- fp32 tiled GEMM: C = A[M,K] @ W[K,N] ----------------
// EPI: 0 = +bias store; 1 = +bias relu store;
//      2 = C = res + gate*(v+bias); 3 = C += gate*(v+bias)
template<int EPI>
__global__ __launch_bounds__(256) void gemm_kernel(
    const float* __restrict__ A, size_t sA,
    const float* __restrict__ W, size_t sW,
    const float* __restrict__ bias, size_t sBias,
    float* __restrict__ C, size_t sC,
    const float* __restrict__ res,
    const float* __restrict__ gates, int GE, int eoff,
    int M, int N, int K)
{
    __shared__ float As[16][132];
    __shared__ float Bs[16][132];
    const int z = blockIdx.z;
    A += (size_t)z * sA; W += (size_t)z * sW; C += (size_t)z * sC;
    const float* bp = bias ? (bias + (size_t)z * sBias) : nullptr;
    const int tid = threadIdx.x;
    const int tx = tid & 15, ty = tid >> 4;
    const int m0 = blockIdx.y * 128, n0 = blockIdx.x * 128;
    float acc[8][8];
    #pragma unroll
    for (int i = 0; i < 8; ++i)
        #pragma unroll
        for (int j = 0; j < 8; ++j) acc[i][j] = 0.f;

    for (int k0 = 0; k0 < K; k0 += 16) {
        #pragma unroll
        for (int lo = 0; lo < 2; ++lo) {
            int u = tid + lo * 256;
            int ar = u >> 2, ak = (u & 3) * 4;
            float4 av = *(const float4*)(A + (size_t)(m0 + ar) * K + k0 + ak);
            As[ak+0][ar] = av.x; As[ak+1][ar] = av.y;
            As[ak+2][ar] = av.z; As[ak+3][ar] = av.w;
            int br = u >> 5, bc = (u & 31) * 4;
            *(float4*)(&Bs[br][bc]) = *(const float4*)(W + (size_t)(k0 + br) * N + n0 + bc);
        }
        __syncthreads();
        #pragma unroll
        for (int k = 0; k < 16; ++k) {
            float4 a0 = *(const float4*)(&As[k][ty*8]);
            float4 a1 = *(const float4*)(&As[k][ty*8+4]);
            float4 b0 = *(const float4*)(&Bs[k][tx*8]);
            float4 b1 = *(const float4*)(&Bs[k][tx*8+4]);
            float a[8] = {a0.x,a0.y,a0.z,a0.w,a1.x,a1.y,a1.z,a1.w};
            float b[8] = {b0.x,b0.y,b0.z,b0.w,b1.x,b1.y,b1.z,b1.w};
            #pragma unroll
            for (int i = 0; i < 8; ++i)
                #pragma unroll
                for (int j = 0; j < 8; ++j)
                    acc[i][j] = fmaf(a[i], b[j], acc[i][j]);
        }
        __syncthreads();
    }
    #pragma unroll
    for (int i = 0; i < 8; ++i) {
        const int r = m0 + ty * 8 + i;
        float g = 0.f;
        if (EPI >= 2) g = gates[(size_t)r * GE + eoff + z];
        #pragma unroll
        for (int jj = 0; jj < 2; ++jj) {
            const int c0 = n0 + tx * 8 + jj * 4;
            float v[4];
            #pragma unroll
            for (int q = 0; q < 4; ++q) {
                v[q] = acc[i][jj*4+q] + (bp ? bp[c0+q] : 0.f);
                if (EPI == 1) v[q] = fmaxf(v[q], 0.f);
            }
            float* cp = C + (size_t)r * N + c0;
            if (EPI <= 1) {
                *(float4*)cp = make_float4(v[0], v[1], v[2], v[3]);
            } else if (EPI == 2) {
                float4 rv = *(const float4*)(res + (size_t)r * N + c0);
                *(float4*)cp = make_float4(rv.x + g*v[0], rv.y + g*v[1],
                                           rv.z + g*v[2], rv.w + g*v[3]);
            } else {
                float4 cv = *(float4*)cp;
                *(float4*)cp = make_float4(cv.x + g*v[0], cv.y + g*v[1],
                                           cv.z + g*v[2], cv.w + g*v[3]);
            }
        }
    }
}

// ---------------- fused flash attention (fp32, 64x64 tiles) ----------------
__global__ __launch_bounds__(256) void flash_kernel(
    const float* __restrict__ q, const float* __restrict__ kbuf,
    const float* __restrict__ vbuf, float* __restrict__ ctx,
    const unsigned char* __restrict__ padmask)
{
    __shared__ float Qs[64][68];   // transposed: [d][q-row]
    __shared__ float KVs[64][68];  // K phase: [d][t] ; V phase: [t][d]
    __shared__ float Ps[64][68];   // [q-row][t]
    const int qt = blockIdx.x, hh = blockIdx.y, z = blockIdx.z;
    const int e = z >> 1, b = z & 1;
    const int tid = threadIdx.x, tx = tid & 15, ty = tid >> 4;
    const size_t ebase = (size_t)e * NTOK * D_DIM;
    const size_t hoff  = (size_t)hh * HDIM;

    #pragma unroll
    for (int lo = 0; lo < 4; ++lo) {
        int u = tid + lo * 256;
        int row = u >> 4, col = (u & 15) * 4;
        int s = qt * 64 + row;
        float4 v = *(const float4*)(q + ebase + (size_t)(s * B_SZ + b) * D_DIM + hoff + col);
        Qs[col+0][row] = v.x; Qs[col+1][row] = v.y;
        Qs[col+2][row] = v.z; Qs[col+3][row] = v.w;
    }
    float m[4], lden[4], acc[4][4];
    #pragma unroll
    for (int i = 0; i < 4; ++i) {
        m[i] = -1e30f; lden[i] = 0.f;
        #pragma unroll
        for (int j = 0; j < 4; ++j) acc[i][j] = 0.f;
    }
    __syncthreads();

    for (int t0 = 0; t0 < S_LEN; t0 += 64) {
        // K tile, transposed into LDS
        #pragma unroll
        for (int lo = 0; lo < 4; ++lo) {
            int u = tid + lo * 256;
            int row = u >> 4, col = (u & 15) * 4;
            float4 v = *(const float4*)(kbuf + (size_t)((t0 + row) * B_SZ + b) * D_DIM + hoff + col);
            KVs[col+0][row] = v.x; KVs[col+1][row] = v.y;
            KVs[col+2][row] = v.z; KVs[col+3][row] = v.w;
        }
        __syncthreads();
        float sc[4][4];
        #pragma unroll
        for (int i = 0; i < 4; ++i)
            #pragma unroll
            for (int j = 0; j < 4; ++j) sc[i][j] = 0.f;
        #pragma unroll
        for (int k = 0; k < 64; ++k) {
            float4 af = *(const float4*)(&Qs[k][ty*4]);
            float4 bf = *(const float4*)(&KVs[k][tx*4]);
            float aa[4] = {af.x, af.y, af.z, af.w};
            float bb[4] = {bf.x, bf.y, bf.z, bf.w};
            #pragma unroll
            for (int i = 0; i < 4; ++i)
                #pragma unroll
                for (int j = 0; j < 4; ++j)
                    sc[i][j] = fmaf(aa[i], bb[j], sc[i][j]);
        }
        #pragma unroll
        for (int j = 0; j < 4; ++j) {
            bool msk = padmask[(size_t)b * S_LEN + t0 + tx*4 + j] != 0;
            #pragma unroll
            for (int i = 0; i < 4; ++i)
                sc[i][j] = msk ? -1e8f : sc[i][j] * 0.125f;
        }
        #pragma unroll
        for (int i = 0; i < 4; ++i) {
            float tm = fmaxf(fmaxf(sc[i][0], sc[i][1]), fmaxf(sc[i][2], sc[i][3]));
            #pragma unroll
            for (int o = 1; o < 16; o <<= 1) tm = fmaxf(tm, __shfl_xor(tm, o));
            float mn = fmaxf(m[i], tm);
            float corr = __expf(m[i] - mn);
            float rsum = 0.f;
            #pragma unroll
            for (int j = 0; j < 4; ++j) { sc[i][j] = __expf(sc[i][j] - mn); rsum += sc[i][j]; }
            #pragma unroll
            for (int o = 1; o < 16; o <<= 1) rsum += __shfl_xor(rsum, o);
            lden[i] = lden[i] * corr + rsum;
            #pragma unroll
            for (int j = 0; j < 4; ++j) acc[i][j] *= corr;
            m[i] = mn;
            *(float4*)(&Ps[ty*4+i][tx*4]) = make_float4(sc[i][0], sc[i][1], sc[i][2], sc[i][3]);
        }
        __syncthreads();
        // V tile, natural layout (overwrites K)
        #pragma unroll
        for (int lo = 0; lo < 4; ++lo) {
            int u = tid + lo * 256;
            int row = u >> 4, col = (u & 15) * 4;
            *(float4*)(&KVs[row][col]) =
                *(const float4*)(vbuf + (size_t)((t0 + row) * B_SZ + b) * D_DIM + hoff + col);
        }
        __syncthreads();
        #pragma unroll
        for (int t4 = 0; t4 < 64; t4 += 4) {
            float p4[4][4];
            #pragma unroll
            for (int i = 0; i < 4; ++i) {
                float4 pv = *(const float4*)(&Ps[ty*4+i][t4]);
                p4[i][0] = pv.x; p4[i][1] = pv.y; p4[i][2] = pv.z; p4[i][3] = pv.w;
            }
            #pragma unroll
            for (int tt = 0; tt < 4; ++tt) {
                float4 vv = *(const float4*)(&KVs[t4+tt][tx*4]);
                #pragma unroll
                for (int i = 0; i < 4; ++i) {
                    acc[i][0] = fmaf(p4[i][tt], vv.x, acc[i][0]);
                    acc[i][1] = fmaf(p4[i][tt], vv.y, acc[i][1]);
                    acc[i][2] = fmaf(p4[i][tt], vv.z, acc[i][2]);
                    acc[i][3] = fmaf(p4[i][tt], vv.w, acc[i][3]);
                }
            }
        }
        __syncthreads();
    }
    #pragma unroll
    for (int i = 0; i < 4; ++i) {
        float inv = 1.0f / lden[i];
        int s = qt*64 + ty*4 + i;
        *(float4*)(ctx + ebase + (size_t)(s * B_SZ + b) * D_DIM + hoff + tx*4) =
            make_float4(acc[i][0]*inv, acc[i][1]*inv, acc[i][2]*inv, acc[i][3]*inv);
    }
}

// ---------------- gated combine of attention experts + residual ----------------
__global__ __launch_bounds__(256) void combine_attn_kernel(
    const float* __restrict__ x, const float* __restrict__ oute,
    const float* __restrict__ gates, float* __restrict__ x2)
{
    const int r = blockIdx.x, t = threadIdx.x;
    const size_t off = (size_t)r * D_DIM + t * 4;
    float g[EA_N];
    #pragma unroll
    for (int e = 0; e < EA_N; ++e) g[e] = gates[(size_t)r * EA_N + e];
    float4 v = *(const float4*)(x + off);
    #pragma unroll
    for (int e = 0; e < EA_N; ++e) {
        float4 o = *(const float4*)(oute + (size_t)e * NTOK * D_DIM + off);
        v.x = fmaf(g[e], o.x, v.x); v.y = fmaf(g[e], o.y, v.y);
        v.z = fmaf(g[e], o.z, v.z); v.w = fmaf(g[e], o.w, v.w);
    }
    *(float4*)(x2 + off) = v;
}

// ---------------- aux loss finalize ----------------
__device__ float aux_from(const float* a, int E) {
    float si = 0.f, sl = 0.f;
    for (int e = 0; e < E; ++e) { si += a[e]; sl += a[E+e]; }
    float mean = si / E;
    float var = 0.f;
    for (int e = 0; e < E; ++e) { float d = a[e] - mean; var += d*d; }
    var /= E;
    float cv = var / (mean*mean + 1e-10f);
    float sw = 0.f;
    for (int e = 0; e < E; ++e) sw += (a[E+e] / (sl + 1e-9f)) * (a[e] / (si + 1e-9f));
    sw *= E;
    float zz = a[2*E] / NTOK;
    return 0.01f * cv + 0.01f * sw + 0.001f * zz;
}

__global__ void finalize_kernel(const float* __restrict__ acc, float* __restrict__ out) {
    if (threadIdx.x == 0 && blockIdx.x == 0)
        out[(size_t)NTOK * D_DIM] = aux_from(acc, EA_N) + aux_from(acc + 32, EF_N);
}

extern "C" void kernel_launch(void* const* d_in, const int* in_sizes, int n_in,
                              void* d_out, int out_size, void* d_ws, size_t ws_size,
                              hipStream_t stream)
{
    const float* x     = (const float*)d_in[0];
    const unsigned char* halt  = (const unsigned char*)d_in[1];
    const unsigned char* pmask = (const unsigned char*)d_in[3];
    const float* ln1s = (const float*)d_in[4];
    const float* ln1b = (const float*)d_in[5];
    const float* ln2s = (const float*)d_in[6];
    const float* ln2b = (const float*)d_in[7];
    const float* Wg_a = (const float*)d_in[8];
    const float* Wq   = (const float*)d_in[9];
    const float* bq   = (const float*)d_in[10];
    const float* Wk   = (const float*)d_in[11];
    const float* bk   = (const float*)d_in[12];
    const float* Wv   = (const float*)d_in[13];
    const float* bv   = (const float*)d_in[14];
    const float* Wo   = (const float*)d_in[15];
    const float* bo   = (const float*)d_in[16];
    const float* Wg_f = (const float*)d_in[17];
    const float* W1   = (const float*)d_in[18];
    const float* b1   = (const float*)d_in[19];
    const float* W2   = (const float*)d_in[20];
    const float* b2   = (const float*)d_in[21];
    float* out = (float*)d_out;

    const size_t TD = (size_t)NTOK * D_DIM;   // 2M floats
    float* ws = (float*)d_ws;
    float* h       = ws;                       // TD (also reused as h2)
    float* kbuf    = h + TD;                   // TD
    float* vbuf    = kbuf + TD;                // TD
    float* x2      = vbuf + TD;                // TD
    float* qall    = x2 + TD;                  // 4*TD (Q experts; reused as out_e)
    float* ctxb    = qall + 4*TD;              // 4*TD
    float* hid     = ctxb + 4*TD;              // NTOK*FF = 4M
    float* logits_a = hid + (size_t)NTOK*FF_DIM;
    float* gates_a  = logits_a + (size_t)NTOK*EA_N;
    float* logits_f = gates_a  + (size_t)NTOK*EA_N;
    float* gates_f  = logits_f + (size_t)NTOK*EF_N;
    float* accs     = gates_f  + (size_t)NTOK*EF_N;   // 64 floats

    hipMemsetAsync(accs, 0, 64 * sizeof(float), stream);

    // ---- attention block ----
    ln_gate_kernel<EA_N><<<NTOK, 256, 0, stream>>>(x, ln1s, ln1b, Wg_a, h, logits_a);
    gating_kernel<EA_N, KA_K><<<NTOK/256, 256, 0, stream>>>(logits_a, halt, gates_a, accs);

    gemm_kernel<0><<<dim3(D_DIM/128, NTOK/128, EA_N), 256, 0, stream>>>(
        h, 0, Wq, (size_t)D_DIM*D_DIM, bq, D_DIM, qall, TD,
        nullptr, nullptr, 0, 0, NTOK, D_DIM, D_DIM);
    gemm_kernel<0><<<dim3(D_DIM/128, NTOK/128, 1), 256, 0, stream>>>(
        h, 0, Wk, 0, bk, 0, kbuf, 0,
        nullptr, nullptr, 0, 0, NTOK, D_DIM, D_DIM);
    gemm_kernel<0><<<dim3(D_DIM/128, NTOK/128, 1), 256, 0, stream>>>(
        h, 0, Wv, 0, bv, 0, vbuf, 0,
        nullptr, nullptr, 0, 0, NTOK, D_DIM, D_DIM);

    flash_kernel<<<dim3(S_LEN/64, NHEAD, EA_N*B_SZ), 256, 0, stream>>>(
        qall, kbuf, vbuf, ctxb, pmask);

    gemm_kernel<0><<<dim3(D_DIM/128, NTOK/128, EA_N), 256, 0, stream>>>(
        ctxb, TD, Wo, (size_t)D_DIM*D_DIM, bo, D_DIM, qall /*out_e*/, TD,
        nullptr, nullptr, 0, 0, NTOK, D_DIM, D_DIM);

    combine_attn_kernel<<<NTOK, 256, 0, stream>>>(x, qall, gates_a, x2);

    // ---- FFN block ----
    ln_gate_kernel<EF_N><<<NTOK, 256, 0, stream>>>(x2, ln2s, ln2b, Wg_f, h, logits_f);
    gating_kernel<EF_N, KF_K><<<NTOK/256, 256, 0, stream>>>(logits_f, halt, gates_f, accs + 32);

    for (int e = 0; e < EF_N; ++e) {
        gemm_kernel<1><<<dim3(FF_DIM/128, NTOK/128, 1), 256, 0, stream>>>(
            h, 0, W1 + (size_t)e*D_DIM*FF_DIM, 0, b1 + (size_t)e*FF_DIM, 0, hid, 0,
            nullptr, nullptr, 0, 0, NTOK, FF_DIM, D_DIM);
        if (e == 0)
            gemm_kernel<2><<<dim3(D_DIM/128, NTOK/128, 1), 256, 0, stream>>>(
                hid, 0, W2 + (size_t)e*FF_DIM*D_DIM, 0, b2 + (size_t)e*D_DIM, 0, out, 0,
                x2, gates_f, EF_N, e, NTOK, D_DIM, FF_DIM);
        else
            gemm_kernel<3><<<dim3(D_DIM/128, NTOK/128, 1), 256, 0, stream>>>(
                hid, 0, W2 + (size_t)e*FF_DIM*D_DIM, 0, b2 + (size_t)e*D_DIM, 0, out, 0,
                x2, gates_f, EF_N, e, NTOK, D_DIM, FF_DIM);
    }

    finalize_kernel<<<1, 64, 0, stream>>>(accs, out);
}

// Round 3
// 2315.633 us; speedup vs baseline: 2.5398x; 2.5398x over previous
//
#include <hip/hip_runtime.h>
#include <hip/hip_bf16.h>
#include <math.h>

#define S_LEN 1024
#define B_SZ  2
#define D_DIM 1024
#define NHEAD 16
#define HDIM  64
#define EA_N  4
#define KA_K  2
#define EF_N  8
#define KF_K  2
#define FF_DIM 2048
#define NTOK  (S_LEN*B_SZ)
#define LN_EPS 1e-5f

typedef short bf16x8 __attribute__((ext_vector_type(8)));
typedef float f32x4 __attribute__((ext_vector_type(4)));

__device__ __forceinline__ unsigned short f2bf(float x) {
    __hip_bfloat16 b = __float2bfloat16(x);
    return *reinterpret_cast<unsigned short*>(&b);
}

__device__ __forceinline__ void gload16(const void* g, void* l) {
    __builtin_amdgcn_global_load_lds(
        (const __attribute__((address_space(1))) void*)g,
        (__attribute__((address_space(3))) void*)l, 16, 0, 0);
}

// ---------------- weight fp32 [K][N] -> bf16 [N][K] transpose ----------------
__global__ __launch_bounds__(256) void convt_kernel(
    const float* __restrict__ W, unsigned short* __restrict__ WT, int K, int N)
{
    __shared__ unsigned short T[32][33];
    const int z = blockIdx.z;
    W  += (size_t)z * K * N;
    WT += (size_t)z * K * N;
    const int tx = threadIdx.x & 31, ty = threadIdx.x >> 5;   // ty 0..7
    const int k0 = blockIdx.y * 32, n0 = blockIdx.x * 32;
    #pragma unroll
    for (int r = 0; r < 4; ++r)
        T[ty + r*8][tx] = f2bf(W[(size_t)(k0 + ty + r*8) * N + n0 + tx]);
    __syncthreads();
    #pragma unroll
    for (int r = 0; r < 4; ++r)
        WT[(size_t)(n0 + ty + r*8) * K + k0 + tx] = T[tx][ty + r*8];
}

// ---------------- LayerNorm + router logits (fused), bf16 h out ----------------
template<int E>
__global__ __launch_bounds__(256) void ln_gate_kernel(
    const float* __restrict__ x, const float* __restrict__ gamma,
    const float* __restrict__ beta, const float* __restrict__ Wg,
    unsigned short* __restrict__ h, float* __restrict__ logits)
{
    __shared__ float rA[4], rB[4], rG[4];
    __shared__ float stat[2];
    const int r = blockIdx.x;
    const int t = threadIdx.x;
    const int lane = t & 63, w = t >> 6;
    const size_t base = (size_t)r * D_DIM + t * 4;
    float4 xv = *(const float4*)(x + base);
    float s  = xv.x + xv.y + xv.z + xv.w;
    float sq = xv.x*xv.x + xv.y*xv.y + xv.z*xv.z + xv.w*xv.w;
    #pragma unroll
    for (int o = 32; o; o >>= 1) { s += __shfl_down(s, o); sq += __shfl_down(sq, o); }
    if (lane == 0) { rA[w] = s; rB[w] = sq; }
    __syncthreads();
    if (t == 0) {
        float ts = rA[0]+rA[1]+rA[2]+rA[3];
        float tq = rB[0]+rB[1]+rB[2]+rB[3];
        float mean = ts * (1.0f / D_DIM);
        float var  = tq * (1.0f / D_DIM) - mean * mean;
        stat[0] = mean;
        stat[1] = rsqrtf(var + LN_EPS);
    }
    __syncthreads();
    const float mean = stat[0], rstd = stat[1];
    float4 g4 = *(const float4*)(gamma + t*4);
    float4 b4 = *(const float4*)(beta  + t*4);
    float hv[4];
    hv[0] = (xv.x - mean) * rstd * g4.x + b4.x;
    hv[1] = (xv.y - mean) * rstd * g4.y + b4.y;
    hv[2] = (xv.z - mean) * rstd * g4.z + b4.z;
    hv[3] = (xv.w - mean) * rstd * g4.w + b4.w;
    uint2 pk;
    pk.x = (unsigned)f2bf(hv[0]) | ((unsigned)f2bf(hv[1]) << 16);
    pk.y = (unsigned)f2bf(hv[2]) | ((unsigned)f2bf(hv[3]) << 16);
    *(uint2*)(h + base) = pk;
    #pragma unroll
    for (int e = 0; e < E; ++e) {
        float p = hv[0]*Wg[(t*4+0)*E+e] + hv[1]*Wg[(t*4+1)*E+e]
                + hv[2]*Wg[(t*4+2)*E+e] + hv[3]*Wg[(t*4+3)*E+e];
        #pragma unroll
        for (int o = 32; o; o >>= 1) p += __shfl_down(p, o);
        if (lane == 0) rG[w] = p;
        __syncthreads();
        if (t == 0) logits[(size_t)r*E + e] = rG[0]+rG[1]+rG[2]+rG[3];
        __syncthreads();
    }
}

// ---------------- softmax + top-k gates + aux accumulators ----------------
template<int E, int K>
__global__ __launch_bounds__(256) void gating_kernel(
    const float* __restrict__ logits, const unsigned char* __restrict__ halt,
    float* __restrict__ gates, float* __restrict__ acc)
{
    const int r = blockIdx.x * 256 + threadIdx.x;
    if (r >= NTOK) return;
    float l[E], p[E];
    float m = -1e30f;
    #pragma unroll
    for (int e = 0; e < E; ++e) { l[e] = logits[(size_t)r*E + e]; m = fmaxf(m, l[e]); }
    float sum = 0.f;
    #pragma unroll
    for (int e = 0; e < E; ++e) { p[e] = expf(l[e] - m); sum += p[e]; }
    const float inv = 1.0f / sum;
    #pragma unroll
    for (int e = 0; e < E; ++e) p[e] *= inv;
    unsigned used = 0u;
    float vsum = 0.f;
    int   idx[K]; float val[K];
    #pragma unroll
    for (int kk = 0; kk < K; ++kk) {
        float best = -1.f; int bi = 0;
        #pragma unroll
        for (int e = 0; e < E; ++e)
            if (!((used >> e) & 1u) && p[e] > best) { best = p[e]; bi = e; }
        idx[kk] = bi; val[kk] = best; used |= (1u << bi); vsum += best;
    }
    const float rn = 1.0f / (vsum + 1e-9f);
    const bool hlt = (halt[r] != 0);
    float g[E];
    #pragma unroll
    for (int e = 0; e < E; ++e) g[e] = 0.f;
    #pragma unroll
    for (int kk = 0; kk < K; ++kk) g[idx[kk]] = val[kk] * rn;
    #pragma unroll
    for (int e = 0; e < E; ++e) {
        float gg = hlt ? 0.f : g[e];
        gates[(size_t)r*E + e] = gg;
        atomicAdd(&acc[e], p[e]);
        if (gg > 0.f) atomicAdd(&acc[E + e], 1.0f);
    }
    const float lse = m + logf(sum);
    atomicAdd(&acc[2*E], lse * lse);
}

// ---------------- bf16 MFMA GEMM: C = A[M,K] @ BT[N,K]^T ----------------
// A row-major bf16 (K contig), BT row-major bf16 (K contig). fp32 accum.
// RELU: relu epilogue. OUTBF: store bf16 else fp32. Always +bias.
template<int RELU, int OUTBF>
__global__ __launch_bounds__(256) void gemm_bf16_kernel(
    const unsigned short* __restrict__ A, size_t sA,
    const unsigned short* __restrict__ BT, size_t sBT,
    const float* __restrict__ bias, size_t sBias,
    void* __restrict__ Cv, size_t sC,
    int M, int N, int K)
{
    __shared__ __align__(16) unsigned short Als[128*32];
    __shared__ __align__(16) unsigned short Bls[128*32];
    const int z = blockIdx.z;
    A  += (size_t)z * sA;
    BT += (size_t)z * sBT;
    const float* bp = bias + (size_t)z * sBias;
    const int tid = threadIdx.x, lane = tid & 63, w = tid >> 6;
    const int wr = w >> 1, wc = w & 1;
    const int m0 = blockIdx.y * 128, n0 = blockIdx.x * 128;
    const int srow = lane >> 2, skoff = (lane & 3) * 8;
    f32x4 acc[4][4];
    #pragma unroll
    for (int i = 0; i < 4; ++i)
        #pragma unroll
        for (int j = 0; j < 4; ++j)
            acc[i][j] = (f32x4){0.f, 0.f, 0.f, 0.f};

    for (int k0 = 0; k0 < K; k0 += 32) {
        #pragma unroll
        for (int i = 0; i < 2; ++i) {
            const int chunk = i*4 + w;
            const int row = chunk*16 + srow;
            gload16(A  + (size_t)(m0+row)*K + k0 + skoff, &Als[chunk*512 + lane*8]);
            gload16(BT + (size_t)(n0+row)*K + k0 + skoff, &Bls[chunk*512 + lane*8]);
        }
        __syncthreads();
        bf16x8 av[4], bv[4];
        const int kg = (lane >> 4) * 8;
        #pragma unroll
        for (int i = 0; i < 4; ++i)
            av[i] = *(const bf16x8*)&Als[(wr*64 + i*16 + (lane&15))*32 + kg];
        #pragma unroll
        for (int j = 0; j < 4; ++j)
            bv[j] = *(const bf16x8*)&Bls[(wc*64 + j*16 + (lane&15))*32 + kg];
        #pragma unroll
        for (int i = 0; i < 4; ++i)
            #pragma unroll
            for (int j = 0; j < 4; ++j)
                acc[i][j] = __builtin_amdgcn_mfma_f32_16x16x32_bf16(av[i], bv[j], acc[i][j], 0, 0, 0);
        __syncthreads();
    }

    const int rbase = (lane >> 4) * 4, cbase = lane & 15;
    #pragma unroll
    for (int i = 0; i < 4; ++i) {
        #pragma unroll
        for (int r = 0; r < 4; ++r) {
            const int row = m0 + wr*64 + i*16 + rbase + r;
            #pragma unroll
            for (int j = 0; j < 4; ++j) {
                const int col = n0 + wc*64 + j*16 + cbase;
                float v = acc[i][j][r] + bp[col];
                if (RELU) v = fmaxf(v, 0.f);
                if (OUTBF)
                    ((unsigned short*)Cv)[(size_t)z*sC + (size_t)row*N + col] = f2bf(v);
                else
                    ((float*)Cv)[(size_t)z*sC + (size_t)row*N + col] = v;
            }
        }
    }
}

// ---------------- fused flash attention (fp32, 64x64 tiles), bf16 ctx out ----
__global__ __launch_bounds__(256) void flash_kernel(
    const float* __restrict__ q, const float* __restrict__ kbuf,
    const float* __restrict__ vbuf, unsigned short* __restrict__ ctx,
    const unsigned char* __restrict__ padmask)
{
    __shared__ float Qs[64][68];
    __shared__ float KVs[64][68];
    __shared__ float Ps[64][68];
    const int qt = blockIdx.x, hh = blockIdx.y, z = blockIdx.z;
    const int e = z >> 1, b = z & 1;
    const int tid = threadIdx.x, tx = tid & 15, ty = tid >> 4;
    const size_t ebase = (size_t)e * NTOK * D_DIM;
    const size_t hoff  = (size_t)hh * HDIM;

    #pragma unroll
    for (int lo = 0; lo < 4; ++lo) {
        int u = tid + lo * 256;
        int row = u >> 4, col = (u & 15) * 4;
        int s = qt * 64 + row;
        float4 v = *(const float4*)(q + ebase + (size_t)(s * B_SZ + b) * D_DIM + hoff + col);
        Qs[col+0][row] = v.x; Qs[col+1][row] = v.y;
        Qs[col+2][row] = v.z; Qs[col+3][row] = v.w;
    }
    float m[4], lden[4], acc[4][4];
    #pragma unroll
    for (int i = 0; i < 4; ++i) {
        m[i] = -1e30f; lden[i] = 0.f;
        #pragma unroll
        for (int j = 0; j < 4; ++j) acc[i][j] = 0.f;
    }
    __syncthreads();

    for (int t0 = 0; t0 < S_LEN; t0 += 64) {
        #pragma unroll
        for (int lo = 0; lo < 4; ++lo) {
            int u = tid + lo * 256;
            int row = u >> 4, col = (u & 15) * 4;
            float4 v = *(const float4*)(kbuf + (size_t)((t0 + row) * B_SZ + b) * D_DIM + hoff + col);
            KVs[col+0][row] = v.x; KVs[col+1][row] = v.y;
            KVs[col+2][row] = v.z; KVs[col+3][row] = v.w;
        }
        __syncthreads();
        float sc[4][4];
        #pragma unroll
        for (int i = 0; i < 4; ++i)
            #pragma unroll
            for (int j = 0; j < 4; ++j) sc[i][j] = 0.f;
        #pragma unroll
        for (int k = 0; k < 64; ++k) {
            float4 af = *(const float4*)(&Qs[k][ty*4]);
            float4 bf = *(const float4*)(&KVs[k][tx*4]);
            float aa[4] = {af.x, af.y, af.z, af.w};
            float bb[4] = {bf.x, bf.y, bf.z, bf.w};
            #pragma unroll
            for (int i = 0; i < 4; ++i)
                #pragma unroll
                for (int j = 0; j < 4; ++j)
                    sc[i][j] = fmaf(aa[i], bb[j], sc[i][j]);
        }
        #pragma unroll
        for (int j = 0; j < 4; ++j) {
            bool msk = padmask[(size_t)b * S_LEN + t0 + tx*4 + j] != 0;
            #pragma unroll
            for (int i = 0; i < 4; ++i)
                sc[i][j] = msk ? -1e8f : sc[i][j] * 0.125f;
        }
        #pragma unroll
        for (int i = 0; i < 4; ++i) {
            float tm = fmaxf(fmaxf(sc[i][0], sc[i][1]), fmaxf(sc[i][2], sc[i][3]));
            #pragma unroll
            for (int o = 1; o < 16; o <<= 1) tm = fmaxf(tm, __shfl_xor(tm, o));
            float mn = fmaxf(m[i], tm);
            float corr = __expf(m[i] - mn);
            float rsum = 0.f;
            #pragma unroll
            for (int j = 0; j < 4; ++j) { sc[i][j] = __expf(sc[i][j] - mn); rsum += sc[i][j]; }
            #pragma unroll
            for (int o = 1; o < 16; o <<= 1) rsum += __shfl_xor(rsum, o);
            lden[i] = lden[i] * corr + rsum;
            #pragma unroll
            for (int j = 0; j < 4; ++j) acc[i][j] *= corr;
            m[i] = mn;
            *(float4*)(&Ps[ty*4+i][tx*4]) = make_float4(sc[i][0], sc[i][1], sc[i][2], sc[i][3]);
        }
        __syncthreads();
        #pragma unroll
        for (int lo = 0; lo < 4; ++lo) {
            int u = tid + lo * 256;
            int row = u >> 4, col = (u & 15) * 4;
            *(float4*)(&KVs[row][col]) =
                *(const float4*)(vbuf + (size_t)((t0 + row) * B_SZ + b) * D_DIM + hoff + col);
        }
        __syncthreads();
        #pragma unroll
        for (int t4 = 0; t4 < 64; t4 += 4) {
            float p4[4][4];
            #pragma unroll
            for (int i = 0; i < 4; ++i) {
                float4 pv = *(const float4*)(&Ps[ty*4+i][t4]);
                p4[i][0] = pv.x; p4[i][1] = pv.y; p4[i][2] = pv.z; p4[i][3] = pv.w;
            }
            #pragma unroll
            for (int tt = 0; tt < 4; ++tt) {
                float4 vv = *(const float4*)(&KVs[t4+tt][tx*4]);
                #pragma unroll
                for (int i = 0; i < 4; ++i) {
                    acc[i][0] = fmaf(p4[i][tt], vv.x, acc[i][0]);
                    acc[i][1] = fmaf(p4[i][tt], vv.y, acc[i][1]);
                    acc[i][2] = fmaf(p4[i][tt], vv.z, acc[i][2]);
                    acc[i][3] = fmaf(p4[i][tt], vv.w, acc[i][3]);
                }
            }
        }
        __syncthreads();
    }
    #pragma unroll
    for (int i = 0; i < 4; ++i) {
        float inv = 1.0f / lden[i];
        int s = qt*64 + ty*4 + i;
        unsigned short* cp = ctx + ebase + (size_t)(s * B_SZ + b) * D_DIM + hoff + tx*4;
        uint2 pk;
        pk.x = (unsigned)f2bf(acc[i][0]*inv) | ((unsigned)f2bf(acc[i][1]*inv) << 16);
        pk.y = (unsigned)f2bf(acc[i][2]*inv) | ((unsigned)f2bf(acc[i][3]*inv) << 16);
        *(uint2*)cp = pk;
    }
}

// ---------------- gated combine of attention experts + residual ----------------
__global__ __launch_bounds__(256) void combine_attn_kernel(
    const float* __restrict__ x, const float* __restrict__ oute,
    const float* __restrict__ gates, float* __restrict__ x2)
{
    const int r = blockIdx.x, t = threadIdx.x;
    const size_t off = (size_t)r * D_DIM + t * 4;
    float g[EA_N];
    #pragma unroll
    for (int e = 0; e < EA_N; ++e) g[e] = gates[(size_t)r * EA_N + e];
    float4 v = *(const float4*)(x + off);
    #pragma unroll
    for (int e = 0; e < EA_N; ++e) {
        float4 o = *(const float4*)(oute + (size_t)e * NTOK * D_DIM + off);
        v.x = fmaf(g[e], o.x, v.x); v.y = fmaf(g[e], o.y, v.y);
        v.z = fmaf(g[e], o.z, v.z); v.w = fmaf(g[e], o.w, v.w);
    }
    *(float4*)(x2 + off) = v;
}

// ---------------- gated combine of 4 FFN experts ----------------
template<int ADD>
__global__ __launch_bounds__(256) void ffn_combine_kernel(
    const float* __restrict__ x2, const float* __restrict__ y4,
    const float* __restrict__ gates, int ebase, float* __restrict__ out)
{
    const int r = blockIdx.x, t = threadIdx.x;
    const size_t off = (size_t)r * D_DIM + t * 4;
    float4 v = ADD ? *(const float4*)(out + off) : *(const float4*)(x2 + off);
    #pragma unroll
    for (int e = 0; e < 4; ++e) {
        float g = gates[(size_t)r * EF_N + ebase + e];
        float4 o = *(const float4*)(y4 + (size_t)e * NTOK * D_DIM + off);
        v.x = fmaf(g, o.x, v.x); v.y = fmaf(g, o.y, v.y);
        v.z = fmaf(g, o.z, v.z); v.w = fmaf(g, o.w, v.w);
    }
    *(float4*)(out + off) = v;
}

// ---------------- aux loss finalize ----------------
__device__ float aux_from(const float* a, int E) {
    float si = 0.f, sl = 0.f;
    for (int e = 0; e < E; ++e) { si += a[e]; sl += a[E+e]; }
    float mean = si / E;
    float var = 0.f;
    for (int e = 0; e < E; ++e) { float d = a[e] - mean; var += d*d; }
    var /= E;
    float cv = var / (mean*mean + 1e-10f);
    float sw = 0.f;
    for (int e = 0; e < E; ++e) sw += (a[E+e] / (sl + 1e-9f)) * (a[e] / (si + 1e-9f));
    sw *= E;
    float zz = a[2*E] / NTOK;
    return 0.01f * cv + 0.01f * sw + 0.001f * zz;
}

__global__ void finalize_kernel(const float* __restrict__ acc, float* __restrict__ out) {
    if (threadIdx.x == 0 && blockIdx.x == 0)
        out[(size_t)NTOK * D_DIM] = aux_from(acc, EA_N) + aux_from(acc + 32, EF_N);
}

extern "C" void kernel_launch(void* const* d_in, const int* in_sizes, int n_in,
                              void* d_out, int out_size, void* d_ws, size_t ws_size,
                              hipStream_t stream)
{
    const float* x     = (const float*)d_in[0];
    const unsigned char* halt  = (const unsigned char*)d_in[1];
    const unsigned char* pmask = (const unsigned char*)d_in[3];
    const float* ln1s = (const float*)d_in[4];
    const float* ln1b = (const float*)d_in[5];
    const float* ln2s = (const float*)d_in[6];
    const float* ln2b = (const float*)d_in[7];
    const float* Wg_a = (const float*)d_in[8];
    const float* Wq   = (const float*)d_in[9];
    const float* bq   = (const float*)d_in[10];
    const float* Wk   = (const float*)d_in[11];
    const float* bk   = (const float*)d_in[12];
    const float* Wv   = (const float*)d_in[13];
    const float* bv   = (const float*)d_in[14];
    const float* Wo   = (const float*)d_in[15];
    const float* bo   = (const float*)d_in[16];
    const float* Wg_f = (const float*)d_in[17];
    const float* W1   = (const float*)d_in[18];
    const float* b1   = (const float*)d_in[19];
    const float* W2   = (const float*)d_in[20];
    const float* b2   = (const float*)d_in[21];
    float* out = (float*)d_out;

    const size_t TD = (size_t)NTOK * D_DIM;          // 2M elems
    const size_t MM = (size_t)1024 * 1024;           // 1M
    char* ws = (char*)d_ws;
    size_t off = 0;
    auto alloc = [&](size_t bytes) { char* p = ws + off; off += (bytes + 255) & ~(size_t)255; return p; };

    unsigned short* WqT = (unsigned short*)alloc(4 * MM * 2);
    unsigned short* KvT = (unsigned short*)alloc(2 * MM * 2);
    unsigned short* WoT = (unsigned short*)alloc(4 * MM * 2);
    unsigned short* W1T = (unsigned short*)alloc(8 * 2 * MM * 2);
    unsigned short* W2T = (unsigned short*)alloc(8 * 2 * MM * 2);
    float*  bkv  = (float*)alloc(2 * 1024 * 4);
    unsigned short* hbf = (unsigned short*)alloc(TD * 2);
    float*  qall = (float*)alloc(4 * TD * 4);        // Q experts / out_e / y4 overlay
    unsigned short* ctxb = (unsigned short*)alloc(4 * TD * 2);
    float*  kv   = (float*)alloc(2 * TD * 4);
    float*  x2   = (float*)alloc(TD * 4);
    unsigned short* hid4 = (unsigned short*)alloc(4 * (size_t)NTOK * FF_DIM * 2);
    float* logits_a = (float*)alloc(NTOK * EA_N * 4);
    float* gates_a  = (float*)alloc(NTOK * EA_N * 4);
    float* logits_f = (float*)alloc(NTOK * EF_N * 4);
    float* gates_f  = (float*)alloc(NTOK * EF_N * 4);
    float* accs     = (float*)alloc(64 * 4);
    float* y4 = qall;                                 // reuse after combine_attn

    hipMemsetAsync(accs, 0, 64 * sizeof(float), stream);
    hipMemcpyAsync(bkv,        bk, 1024 * sizeof(float), hipMemcpyDeviceToDevice, stream);
    hipMemcpyAsync(bkv + 1024, bv, 1024 * sizeof(float), hipMemcpyDeviceToDevice, stream);

    // ---- weight convert+transpose (fp32 [K][N] -> bf16 [N][K]) ----
    convt_kernel<<<dim3(32, 32, 4), 256, 0, stream>>>(Wq, WqT, 1024, 1024);
    convt_kernel<<<dim3(32, 32, 1), 256, 0, stream>>>(Wk, KvT,        1024, 1024);
    convt_kernel<<<dim3(32, 32, 1), 256, 0, stream>>>(Wv, KvT + MM,   1024, 1024);
    convt_kernel<<<dim3(32, 32, 4), 256, 0, stream>>>(Wo, WoT, 1024, 1024);
    convt_kernel<<<dim3(64, 32, 8), 256, 0, stream>>>(W1, W1T, 1024, 2048);
    convt_kernel<<<dim3(32, 64, 8), 256, 0, stream>>>(W2, W2T, 2048, 1024);

    // ---- attention block ----
    ln_gate_kernel<EA_N><<<NTOK, 256, 0, stream>>>(x, ln1s, ln1b, Wg_a, hbf, logits_a);
    gating_kernel<EA_N, KA_K><<<NTOK/256, 256, 0, stream>>>(logits_a, halt, gates_a, accs);

    gemm_bf16_kernel<0,0><<<dim3(8, 16, 4), 256, 0, stream>>>(
        hbf, 0, WqT, MM, bq, 1024, qall, TD, NTOK, 1024, 1024);
    gemm_bf16_kernel<0,0><<<dim3(8, 16, 2), 256, 0, stream>>>(
        hbf, 0, KvT, MM, bkv, 1024, kv, TD, NTOK, 1024, 1024);

    flash_kernel<<<dim3(S_LEN/64, NHEAD, EA_N*B_SZ), 256, 0, stream>>>(
        qall, kv, kv + TD, ctxb, pmask);

    gemm_bf16_kernel<0,0><<<dim3(8, 16, 4), 256, 0, stream>>>(
        ctxb, TD, WoT, MM, bo, 1024, qall /*out_e*/, TD, NTOK, 1024, 1024);

    combine_attn_kernel<<<NTOK, 256, 0, stream>>>(x, qall, gates_a, x2);

    // ---- FFN block ----
    ln_gate_kernel<EF_N><<<NTOK, 256, 0, stream>>>(x2, ln2s, ln2b, Wg_f, hbf, logits_f);
    gating_kernel<EF_N, KF_K><<<NTOK/256, 256, 0, stream>>>(logits_f, halt, gates_f, accs + 32);

    // batch 0: experts 0-3
    gemm_bf16_kernel<1,1><<<dim3(16, 16, 4), 256, 0, stream>>>(
        hbf, 0, W1T, 2*MM, b1, FF_DIM, hid4, (size_t)NTOK*FF_DIM, NTOK, FF_DIM, 1024);
    gemm_bf16_kernel<0,0><<<dim3(8, 16, 4), 256, 0, stream>>>(
        hid4, (size_t)NTOK*FF_DIM, W2T, 2*MM, b2, 1024, y4, TD, NTOK, 1024, FF_DIM);
    ffn_combine_kernel<0><<<NTOK, 256, 0, stream>>>(x2, y4, gates_f, 0, out);

    // batch 1: experts 4-7
    gemm_bf16_kernel<1,1><<<dim3(16, 16, 4), 256, 0, stream>>>(
        hbf, 0, W1T + 4*2*MM, 2*MM, b1 + 4*FF_DIM, FF_DIM, hid4, (size_t)NTOK*FF_DIM, NTOK, FF_DIM, 1024);
    gemm_bf16_kernel<0,0><<<dim3(8, 16, 4), 256, 0, stream>>>(
        hid4, (size_t)NTOK*FF_DIM, W2T + 4*2*MM, 2*MM, b2 + 4*1024, 1024, y4, TD, NTOK, 1024, FF_DIM);
    ffn_combine_kernel<1><<<NTOK, 256, 0, stream>>>(x2, y4, gates_f, 4, out);

    finalize_kernel<<<1, 64, 0, stream>>>(accs, out);
}

// Round 4
// 837.529 us; speedup vs baseline: 7.0221x; 2.7648x over previous
//
#include <hip/hip_runtime.h>
#include <hip/hip_bf16.h>
#include <math.h>

#define S_LEN 1024
#define B_SZ  2
#define D_DIM 1024
#define NHEAD 16
#define HDIM  64
#define EA_N  4
#define KA_K  2
#define EF_N  8
#define KF_K  2
#define FF_DIM 2048
#define NTOK  (S_LEN*B_SZ)
#define LN_EPS 1e-5f

typedef short bf16x8 __attribute__((ext_vector_type(8)));
typedef float f32x4 __attribute__((ext_vector_type(4)));

__device__ __forceinline__ unsigned short f2bf(float x) {
    __hip_bfloat16 b = __float2bfloat16(x);
    return *reinterpret_cast<unsigned short*>(&b);
}
__device__ __forceinline__ float bf2f(unsigned short u) {
    return __uint_as_float((unsigned)u << 16);
}

__device__ __forceinline__ void gload16(const void* g, void* l) {
    __builtin_amdgcn_global_load_lds(
        (const __attribute__((address_space(1))) void*)g,
        (__attribute__((address_space(3))) void*)l, 16, 0, 0);
}

// ---------------- weight fp32 [K][N] -> bf16 [N][K] transpose ----------------
__global__ __launch_bounds__(256) void convt_kernel(
    const float* __restrict__ W, unsigned short* __restrict__ WT, int K, int N)
{
    __shared__ unsigned short T[32][33];
    const int z = blockIdx.z;
    W  += (size_t)z * K * N;
    WT += (size_t)z * K * N;
    const int tx = threadIdx.x & 31, ty = threadIdx.x >> 5;
    const int k0 = blockIdx.y * 32, n0 = blockIdx.x * 32;
    #pragma unroll
    for (int r = 0; r < 4; ++r)
        T[ty + r*8][tx] = f2bf(W[(size_t)(k0 + ty + r*8) * N + n0 + tx]);
    __syncthreads();
    #pragma unroll
    for (int r = 0; r < 4; ++r)
        WT[(size_t)(n0 + ty + r*8) * K + k0 + tx] = T[tx][ty + r*8];
}

// ---------------- LayerNorm + router logits (fused), bf16 h out ----------------
template<int E>
__global__ __launch_bounds__(256) void ln_gate_kernel(
    const float* __restrict__ x, const float* __restrict__ gamma,
    const float* __restrict__ beta, const float* __restrict__ Wg,
    unsigned short* __restrict__ h, float* __restrict__ logits)
{
    __shared__ float rA[4], rB[4], rG[4];
    __shared__ float stat[2];
    const int r = blockIdx.x;
    const int t = threadIdx.x;
    const int lane = t & 63, w = t >> 6;
    const size_t base = (size_t)r * D_DIM + t * 4;
    float4 xv = *(const float4*)(x + base);
    float s  = xv.x + xv.y + xv.z + xv.w;
    float sq = xv.x*xv.x + xv.y*xv.y + xv.z*xv.z + xv.w*xv.w;
    #pragma unroll
    for (int o = 32; o; o >>= 1) { s += __shfl_down(s, o); sq += __shfl_down(sq, o); }
    if (lane == 0) { rA[w] = s; rB[w] = sq; }
    __syncthreads();
    if (t == 0) {
        float ts = rA[0]+rA[1]+rA[2]+rA[3];
        float tq = rB[0]+rB[1]+rB[2]+rB[3];
        float mean = ts * (1.0f / D_DIM);
        float var  = tq * (1.0f / D_DIM) - mean * mean;
        stat[0] = mean;
        stat[1] = rsqrtf(var + LN_EPS);
    }
    __syncthreads();
    const float mean = stat[0], rstd = stat[1];
    float4 g4 = *(const float4*)(gamma + t*4);
    float4 b4 = *(const float4*)(beta  + t*4);
    float hv[4];
    hv[0] = (xv.x - mean) * rstd * g4.x + b4.x;
    hv[1] = (xv.y - mean) * rstd * g4.y + b4.y;
    hv[2] = (xv.z - mean) * rstd * g4.z + b4.z;
    hv[3] = (xv.w - mean) * rstd * g4.w + b4.w;
    uint2 pk;
    pk.x = (unsigned)f2bf(hv[0]) | ((unsigned)f2bf(hv[1]) << 16);
    pk.y = (unsigned)f2bf(hv[2]) | ((unsigned)f2bf(hv[3]) << 16);
    *(uint2*)(h + base) = pk;
    #pragma unroll
    for (int e = 0; e < E; ++e) {
        float p = hv[0]*Wg[(t*4+0)*E+e] + hv[1]*Wg[(t*4+1)*E+e]
                + hv[2]*Wg[(t*4+2)*E+e] + hv[3]*Wg[(t*4+3)*E+e];
        #pragma unroll
        for (int o = 32; o; o >>= 1) p += __shfl_down(p, o);
        if (lane == 0) rG[w] = p;
        __syncthreads();
        if (t == 0) logits[(size_t)r*E + e] = rG[0]+rG[1]+rG[2]+rG[3];
        __syncthreads();
    }
}

// ---------------- softmax + top-k gates + aux accumulators ----------------
template<int E, int K>
__global__ __launch_bounds__(256) void gating_kernel(
    const float* __restrict__ logits, const unsigned char* __restrict__ halt,
    float* __restrict__ gates, float* __restrict__ acc)
{
    const int r = blockIdx.x * 256 + threadIdx.x;
    if (r >= NTOK) return;
    float l[E], p[E];
    float m = -1e30f;
    #pragma unroll
    for (int e = 0; e < E; ++e) { l[e] = logits[(size_t)r*E + e]; m = fmaxf(m, l[e]); }
    float sum = 0.f;
    #pragma unroll
    for (int e = 0; e < E; ++e) { p[e] = expf(l[e] - m); sum += p[e]; }
    const float inv = 1.0f / sum;
    #pragma unroll
    for (int e = 0; e < E; ++e) p[e] *= inv;
    unsigned used = 0u;
    float vsum = 0.f;
    int   idx[K]; float val[K];
    #pragma unroll
    for (int kk = 0; kk < K; ++kk) {
        float best = -1.f; int bi = 0;
        #pragma unroll
        for (int e = 0; e < E; ++e)
            if (!((used >> e) & 1u) && p[e] > best) { best = p[e]; bi = e; }
        idx[kk] = bi; val[kk] = best; used |= (1u << bi); vsum += best;
    }
    const float rn = 1.0f / (vsum + 1e-9f);
    const bool hlt = (halt[r] != 0);
    float g[E];
    #pragma unroll
    for (int e = 0; e < E; ++e) g[e] = 0.f;
    #pragma unroll
    for (int kk = 0; kk < K; ++kk) g[idx[kk]] = val[kk] * rn;
    #pragma unroll
    for (int e = 0; e < E; ++e) {
        float gg = hlt ? 0.f : g[e];
        gates[(size_t)r*E + e] = gg;
        atomicAdd(&acc[e], p[e]);
        if (gg > 0.f) atomicAdd(&acc[E + e], 1.0f);
    }
    const float lse = m + logf(sum);
    atomicAdd(&acc[2*E], lse * lse);
}

// ---------------- bf16 MFMA GEMM: C = A[M,K] @ BT[N,K]^T ----------------
// MODE: 0 fp32 row-major, 1 bf16 row-major, 2 bf16 Q-layout [e][b][h][s][d],
//       3 bf16 K-layout [b][h][t][d], 4 bf16 V-transposed [b][h][d][t]
template<int RELU, int MODE>
__global__ __launch_bounds__(256) void gemm_bf16_kernel(
    const unsigned short* __restrict__ A, size_t sA,
    const unsigned short* __restrict__ BT, size_t sBT,
    const float* __restrict__ bias, size_t sBias,
    void* __restrict__ Cv, size_t sC,
    int M, int N, int K)
{
    __shared__ __align__(16) unsigned short Als[128*32];
    __shared__ __align__(16) unsigned short Bls[128*32];
    const int z = blockIdx.z;
    A  += (size_t)z * sA;
    BT += (size_t)z * sBT;
    const float* bp = bias + (size_t)z * sBias;
    const int tid = threadIdx.x, lane = tid & 63, w = tid >> 6;
    const int wr = w >> 1, wc = w & 1;
    const int m0 = blockIdx.y * 128, n0 = blockIdx.x * 128;
    const int srow = lane >> 2, skoff = (lane & 3) * 8;
    f32x4 acc[4][4];
    #pragma unroll
    for (int i = 0; i < 4; ++i)
        #pragma unroll
        for (int j = 0; j < 4; ++j)
            acc[i][j] = (f32x4){0.f, 0.f, 0.f, 0.f};

    for (int k0 = 0; k0 < K; k0 += 32) {
        #pragma unroll
        for (int i = 0; i < 2; ++i) {
            const int chunk = i*4 + w;
            const int row = chunk*16 + srow;
            gload16(A  + (size_t)(m0+row)*K + k0 + skoff, &Als[chunk*512 + lane*8]);
            gload16(BT + (size_t)(n0+row)*K + k0 + skoff, &Bls[chunk*512 + lane*8]);
        }
        __syncthreads();
        bf16x8 av[4], bv[4];
        const int kg = (lane >> 4) * 8;
        #pragma unroll
        for (int i = 0; i < 4; ++i)
            av[i] = *(const bf16x8*)&Als[(wr*64 + i*16 + (lane&15))*32 + kg];
        #pragma unroll
        for (int j = 0; j < 4; ++j)
            bv[j] = *(const bf16x8*)&Bls[(wc*64 + j*16 + (lane&15))*32 + kg];
        #pragma unroll
        for (int i = 0; i < 4; ++i)
            #pragma unroll
            for (int j = 0; j < 4; ++j)
                acc[i][j] = __builtin_amdgcn_mfma_f32_16x16x32_bf16(av[i], bv[j], acc[i][j], 0, 0, 0);
        __syncthreads();
    }

    const int rbase = (lane >> 4) * 4, cbase = lane & 15;
    #pragma unroll
    for (int i = 0; i < 4; ++i) {
        #pragma unroll
        for (int r = 0; r < 4; ++r) {
            const int row = m0 + wr*64 + i*16 + rbase + r;
            #pragma unroll
            for (int j = 0; j < 4; ++j) {
                const int col = n0 + wc*64 + j*16 + cbase;
                float v = acc[i][j][r] + bp[col];
                if (RELU) v = fmaxf(v, 0.f);
                if (MODE == 0) {
                    ((float*)Cv)[(size_t)z*sC + (size_t)row*N + col] = v;
                } else if (MODE == 1) {
                    ((unsigned short*)Cv)[(size_t)z*sC + (size_t)row*N + col] = f2bf(v);
                } else if (MODE == 2) {
                    const int b = row & 1, s = row >> 1, hh = col >> 6, d = col & 63;
                    ((unsigned short*)Cv)[(((size_t)(z*2 + b)*16 + hh) << 16) + (s << 6) + d] = f2bf(v);
                } else if (MODE == 3) {
                    const int b = row & 1, s = row >> 1, hh = col >> 6, d = col & 63;
                    ((unsigned short*)Cv)[(((size_t)b*16 + hh) << 16) + (s << 6) + d] = f2bf(v);
                } else {
                    const int b = row & 1, s = row >> 1, hh = col >> 6, d = col & 63;
                    ((unsigned short*)Cv)[(((size_t)b*16 + hh) << 16) + ((size_t)d << 10) + s] = f2bf(v);
                }
            }
        }
    }
}

// ---------------- bf16 MFMA flash attention ----------------
// Q [e][b][h][s][d], K [b][h][t][d], VT [b][h][d][t] -> ctx bf16 [e][s*2+b][h*64+d]
__global__ __launch_bounds__(256) void flash_mfma_kernel(
    const unsigned short* __restrict__ Q,
    const unsigned short* __restrict__ Kb,
    const unsigned short* __restrict__ Vt,
    unsigned short* __restrict__ ctx,
    const unsigned char* __restrict__ padmask)
{
    __shared__ __align__(16) unsigned short Kls[64*64];
    __shared__ __align__(16) unsigned short Vls[64*64];
    __shared__ __align__(16) unsigned short Pls[64*64];
    const int qt = blockIdx.x, h = blockIdx.y, z = blockIdx.z;
    const int e = z >> 1, b = z & 1;
    const int tid = threadIdx.x, lane = tid & 63, w = tid >> 6;
    const int l15 = lane & 15, lg = lane >> 4;
    const size_t qbase = ((size_t)(e*2 + b)*16 + h) << 16;
    const size_t kbase = ((size_t)(b*16 + h)) << 16;

    // Q fragments in registers (row = lane&15, k contiguous 8 per k-group)
    bf16x8 qa[2];
    {
        const int qrow = qt*64 + w*16 + l15;
        #pragma unroll
        for (int ks = 0; ks < 2; ++ks)
            qa[ks] = *(const bf16x8*)(Q + qbase + (size_t)qrow*64 + ks*32 + lg*8);
    }
    f32x4 po[4];
    float mrow[4], lrow[4];
    #pragma unroll
    for (int j = 0; j < 4; ++j) po[j] = (f32x4){0.f,0.f,0.f,0.f};
    #pragma unroll
    for (int r = 0; r < 4; ++r) { mrow[r] = -1e30f; lrow[r] = 0.f; }

    const int srow = tid >> 3, schunk = tid & 7;   // staging: 64 rows x 8 chunks(16B)

    for (int t0 = 0; t0 < S_LEN; t0 += 64) {
        #pragma unroll
        for (int it = 0; it < 2; ++it) {
            const int row = srow + it*32;
            const int sw = (row & 7) << 4;
            uint4 kd = *(const uint4*)(Kb + kbase + (size_t)(t0+row)*64 + schunk*8);
            uint4 vd = *(const uint4*)(Vt + kbase + (size_t)row*1024 + t0 + schunk*8);
            *(uint4*)((char*)Kls + row*128 + ((schunk*16) ^ sw)) = kd;
            *(uint4*)((char*)Vls + row*128 + ((schunk*16) ^ sw)) = vd;
        }
        __syncthreads();

        // QK^T: sc[j][r] = score[q = w*16+lg*4+r][t = t0 + j*16 + l15]
        f32x4 sc[4];
        #pragma unroll
        for (int j = 0; j < 4; ++j) sc[j] = (f32x4){0.f,0.f,0.f,0.f};
        #pragma unroll
        for (int j = 0; j < 4; ++j) {
            const int trow = j*16 + l15;
            const int swt = (trow & 7) << 4;
            #pragma unroll
            for (int ks = 0; ks < 2; ++ks) {
                bf16x8 kb = *(const bf16x8*)((char*)Kls + trow*128 + ((ks*64 + lg*16) ^ swt));
                sc[j] = __builtin_amdgcn_mfma_f32_16x16x32_bf16(qa[ks], kb, sc[j], 0, 0, 0);
            }
        }
        bool msk[4];
        #pragma unroll
        for (int j = 0; j < 4; ++j)
            msk[j] = padmask[(size_t)b * S_LEN + t0 + j*16 + l15] != 0;

        #pragma unroll
        for (int r = 0; r < 4; ++r) {
            float sv[4];
            #pragma unroll
            for (int j = 0; j < 4; ++j)
                sv[j] = msk[j] ? -1e8f : sc[j][r] * 0.125f;
            float tm = fmaxf(fmaxf(sv[0], sv[1]), fmaxf(sv[2], sv[3]));
            #pragma unroll
            for (int o = 1; o < 16; o <<= 1) tm = fmaxf(tm, __shfl_xor(tm, o));
            const float mn = fmaxf(mrow[r], tm);
            const float corr = __expf(mrow[r] - mn);
            float rs = 0.f;
            #pragma unroll
            for (int j = 0; j < 4; ++j) { sv[j] = __expf(sv[j] - mn); rs += sv[j]; }
            #pragma unroll
            for (int o = 1; o < 16; o <<= 1) rs += __shfl_xor(rs, o);
            lrow[r] = lrow[r] * corr + rs;
            mrow[r] = mn;
            #pragma unroll
            for (int dj = 0; dj < 4; ++dj) po[dj][r] *= corr;
            const int ql = w*16 + lg*4 + r;
            const int swp = (ql & 7) << 4;
            #pragma unroll
            for (int j = 0; j < 4; ++j)
                *(unsigned short*)((char*)Pls + ql*128 + (((j*16 + l15)*2) ^ swp)) = f2bf(sv[j]);
        }

        // PV: po[dj][r] += P[q][t] * V[t][d], d = dj*16 + l15 (wave-local P rows)
        {
            const int ql = w*16 + l15;
            const int swq = (ql & 7) << 4;
            #pragma unroll
            for (int ks = 0; ks < 2; ++ks) {
                bf16x8 pa = *(const bf16x8*)((char*)Pls + ql*128 + ((ks*64 + lg*16) ^ swq));
                #pragma unroll
                for (int dj = 0; dj < 4; ++dj) {
                    const int dl = dj*16 + l15;
                    const int swv = (dl & 7) << 4;
                    bf16x8 vb = *(const bf16x8*)((char*)Vls + dl*128 + ((ks*64 + lg*16) ^ swv));
                    po[dj] = __builtin_amdgcn_mfma_f32_16x16x32_bf16(pa, vb, po[dj], 0, 0, 0);
                }
            }
        }
        __syncthreads();
    }

    #pragma unroll
    for (int r = 0; r < 4; ++r) {
        const int q = qt*64 + w*16 + lg*4 + r;
        const float inv = 1.0f / lrow[r];
        #pragma unroll
        for (int dj = 0; dj < 4; ++dj)
            ctx[(size_t)e*NTOK*D_DIM + (size_t)(q*2 + b)*1024 + h*64 + dj*16 + l15] =
                f2bf(po[dj][r] * inv);
    }
}

// ---------------- gated combine of attention experts + residual ----------------
__global__ __launch_bounds__(256) void combine_attn_kernel(
    const float* __restrict__ x, const unsigned short* __restrict__ oute,
    const float* __restrict__ gates, float* __restrict__ x2)
{
    const int r = blockIdx.x, t = threadIdx.x;
    const size_t off = (size_t)r * D_DIM + t * 4;
    float g[EA_N];
    #pragma unroll
    for (int e = 0; e < EA_N; ++e) g[e] = gates[(size_t)r * EA_N + e];
    float4 v = *(const float4*)(x + off);
    #pragma unroll
    for (int e = 0; e < EA_N; ++e) {
        uint2 o = *(const uint2*)(oute + (size_t)e * NTOK * D_DIM + off);
        v.x = fmaf(g[e], bf2f(o.x & 0xffff), v.x);
        v.y = fmaf(g[e], bf2f(o.x >> 16),    v.y);
        v.z = fmaf(g[e], bf2f(o.y & 0xffff), v.z);
        v.w = fmaf(g[e], bf2f(o.y >> 16),    v.w);
    }
    *(float4*)(x2 + off) = v;
}

// ---------------- gated combine of 4 FFN experts ----------------
template<int ADD>
__global__ __launch_bounds__(256) void ffn_combine_kernel(
    const float* __restrict__ x2, const unsigned short* __restrict__ y4,
    const float* __restrict__ gates, int ebase, float* __restrict__ out)
{
    const int r = blockIdx.x, t = threadIdx.x;
    const size_t off = (size_t)r * D_DIM + t * 4;
    float4 v = ADD ? *(const float4*)(out + off) : *(const float4*)(x2 + off);
    #pragma unroll
    for (int e = 0; e < 4; ++e) {
        float g = gates[(size_t)r * EF_N + ebase + e];
        uint2 o = *(const uint2*)(y4 + (size_t)e * NTOK * D_DIM + off);
        v.x = fmaf(g, bf2f(o.x & 0xffff), v.x);
        v.y = fmaf(g, bf2f(o.x >> 16),    v.y);
        v.z = fmaf(g, bf2f(o.y & 0xffff), v.z);
        v.w = fmaf(g, bf2f(o.y >> 16),    v.w);
    }
    *(float4*)(out + off) = v;
}

// ---------------- aux loss finalize ----------------
__device__ float aux_from(const float* a, int E) {
    float si = 0.f, sl = 0.f;
    for (int e = 0; e < E; ++e) { si += a[e]; sl += a[E+e]; }
    float mean = si / E;
    float var = 0.f;
    for (int e = 0; e < E; ++e) { float d = a[e] - mean; var += d*d; }
    var /= E;
    float cv = var / (mean*mean + 1e-10f);
    float sw = 0.f;
    for (int e = 0; e < E; ++e) sw += (a[E+e] / (sl + 1e-9f)) * (a[e] / (si + 1e-9f));
    sw *= E;
    float zz = a[2*E] / NTOK;
    return 0.01f * cv + 0.01f * sw + 0.001f * zz;
}

__global__ void finalize_kernel(const float* __restrict__ acc, float* __restrict__ out) {
    if (threadIdx.x == 0 && blockIdx.x == 0)
        out[(size_t)NTOK * D_DIM] = aux_from(acc, EA_N) + aux_from(acc + 32, EF_N);
}

extern "C" void kernel_launch(void* const* d_in, const int* in_sizes, int n_in,
                              void* d_out, int out_size, void* d_ws, size_t ws_size,
                              hipStream_t stream)
{
    const float* x     = (const float*)d_in[0];
    const unsigned char* halt  = (const unsigned char*)d_in[1];
    const unsigned char* pmask = (const unsigned char*)d_in[3];
    const float* ln1s = (const float*)d_in[4];
    const float* ln1b = (const float*)d_in[5];
    const float* ln2s = (const float*)d_in[6];
    const float* ln2b = (const float*)d_in[7];
    const float* Wg_a = (const float*)d_in[8];
    const float* Wq   = (const float*)d_in[9];
    const float* bq   = (const float*)d_in[10];
    const float* Wk   = (const float*)d_in[11];
    const float* bk   = (const float*)d_in[12];
    const float* Wv   = (const float*)d_in[13];
    const float* bv   = (const float*)d_in[14];
    const float* Wo   = (const float*)d_in[15];
    const float* bo   = (const float*)d_in[16];
    const float* Wg_f = (const float*)d_in[17];
    const float* W1   = (const float*)d_in[18];
    const float* b1   = (const float*)d_in[19];
    const float* W2   = (const float*)d_in[20];
    const float* b2   = (const float*)d_in[21];
    float* out = (float*)d_out;

    const size_t TD = (size_t)NTOK * D_DIM;          // 2M elems
    const size_t MM = (size_t)1024 * 1024;
    char* ws = (char*)d_ws;
    size_t off = 0;
    auto alloc = [&](size_t bytes) { char* p = ws + off; off += (bytes + 255) & ~(size_t)255; return p; };

    unsigned short* WqT = (unsigned short*)alloc(4 * MM * 2);
    unsigned short* KvT = (unsigned short*)alloc(2 * MM * 2);
    unsigned short* WoT = (unsigned short*)alloc(4 * MM * 2);
    unsigned short* W1T = (unsigned short*)alloc(8 * 2 * MM * 2);
    unsigned short* W2T = (unsigned short*)alloc(8 * 2 * MM * 2);
    unsigned short* hbf  = (unsigned short*)alloc(TD * 2);
    unsigned short* qatt = (unsigned short*)alloc(4 * TD * 2);   // [e][b][h][s][d]
    unsigned short* katt = (unsigned short*)alloc(TD * 2);       // [b][h][t][d]
    unsigned short* vatt = (unsigned short*)alloc(TD * 2);       // [b][h][d][t]
    unsigned short* big  = (unsigned short*)alloc(4 * (size_t)NTOK * FF_DIM * 2); // ctx overlay hid4
    unsigned short* oute = (unsigned short*)alloc(4 * TD * 2);   // attn out_e / FFN y4
    float*  x2   = (float*)alloc(TD * 4);
    float* logits_a = (float*)alloc(NTOK * EA_N * 4);
    float* gates_a  = (float*)alloc(NTOK * EA_N * 4);
    float* logits_f = (float*)alloc(NTOK * EF_N * 4);
    float* gates_f  = (float*)alloc(NTOK * EF_N * 4);
    float* accs     = (float*)alloc(64 * 4);
    unsigned short* ctxb = big;          // 4*TD bf16 (attention phase)
    unsigned short* hid4 = big;          // 4*NTOK*FF bf16 (FFN phase)
    unsigned short* y4   = oute;         // reuse after combine_attn

    hipMemsetAsync(accs, 0, 64 * sizeof(float), stream);

    // ---- weight convert+transpose (fp32 [K][N] -> bf16 [N][K]) ----
    convt_kernel<<<dim3(32, 32, 4), 256, 0, stream>>>(Wq, WqT, 1024, 1024);
    convt_kernel<<<dim3(32, 32, 1), 256, 0, stream>>>(Wk, KvT,      1024, 1024);
    convt_kernel<<<dim3(32, 32, 1), 256, 0, stream>>>(Wv, KvT + MM, 1024, 1024);
    convt_kernel<<<dim3(32, 32, 4), 256, 0, stream>>>(Wo, WoT, 1024, 1024);
    convt_kernel<<<dim3(64, 32, 8), 256, 0, stream>>>(W1, W1T, 1024, 2048);
    convt_kernel<<<dim3(32, 64, 8), 256, 0, stream>>>(W2, W2T, 2048, 1024);

    // ---- attention block ----
    ln_gate_kernel<EA_N><<<NTOK, 256, 0, stream>>>(x, ln1s, ln1b, Wg_a, hbf, logits_a);
    gating_kernel<EA_N, KA_K><<<NTOK/256, 256, 0, stream>>>(logits_a, halt, gates_a, accs);

    gemm_bf16_kernel<0,2><<<dim3(8, 16, 4), 256, 0, stream>>>(
        hbf, 0, WqT, MM, bq, 1024, qatt, 0, NTOK, 1024, 1024);
    gemm_bf16_kernel<0,3><<<dim3(8, 16, 1), 256, 0, stream>>>(
        hbf, 0, KvT, 0, bk, 0, katt, 0, NTOK, 1024, 1024);
    gemm_bf16_kernel<0,4><<<dim3(8, 16, 1), 256, 0, stream>>>(
        hbf, 0, KvT + MM, 0, bv, 0, vatt, 0, NTOK, 1024, 1024);

    flash_mfma_kernel<<<dim3(S_LEN/64, NHEAD, EA_N*B_SZ), 256, 0, stream>>>(
        qatt, katt, vatt, ctxb, pmask);

    gemm_bf16_kernel<0,1><<<dim3(8, 16, 4), 256, 0, stream>>>(
        ctxb, TD, WoT, MM, bo, 1024, oute, TD, NTOK, 1024, 1024);

    combine_attn_kernel<<<NTOK, 256, 0, stream>>>(x, oute, gates_a, x2);

    // ---- FFN block ----
    ln_gate_kernel<EF_N><<<NTOK, 256, 0, stream>>>(x2, ln2s, ln2b, Wg_f, hbf, logits_f);
    gating_kernel<EF_N, KF_K><<<NTOK/256, 256, 0, stream>>>(logits_f, halt, gates_f, accs + 32);

    // batch 0: experts 0-3
    gemm_bf16_kernel<1,1><<<dim3(16, 16, 4), 256, 0, stream>>>(
        hbf, 0, W1T, 2*MM, b1, FF_DIM, hid4, (size_t)NTOK*FF_DIM, NTOK, FF_DIM, 1024);
    gemm_bf16_kernel<0,1><<<dim3(8, 16, 4), 256, 0, stream>>>(
        hid4, (size_t)NTOK*FF_DIM, W2T, 2*MM, b2, 1024, y4, TD, NTOK, 1024, FF_DIM);
    ffn_combine_kernel<0><<<NTOK, 256, 0, stream>>>(x2, y4, gates_f, 0, out);

    // batch 1: experts 4-7
    gemm_bf16_kernel<1,1><<<dim3(16, 16, 4), 256, 0, stream>>>(
        hbf, 0, W1T + 4*2*MM, 2*MM, b1 + 4*FF_DIM, FF_DIM, hid4, (size_t)NTOK*FF_DIM, NTOK, FF_DIM, 1024);
    gemm_bf16_kernel<0,1><<<dim3(8, 16, 4), 256, 0, stream>>>(
        hid4, (size_t)NTOK*FF_DIM, W2T + 4*2*MM, 2*MM, b2 + 4*1024, 1024, y4, TD, NTOK, 1024, FF_DIM);
    ffn_combine_kernel<1><<<NTOK, 256, 0, stream>>>(x2, y4, gates_f, 4, out);

    finalize_kernel<<<1, 64, 0, stream>>>(accs, out);
}